// Round 4
// baseline (215.421 us; speedup 1.0000x reference)
//
#include <hip/hip_runtime.h>
#include <hip/hip_bf16.h>

// GraphSAGE 2-layer, mean agg, D=64, fp32 in/out.
// R9:  bf16 node features everywhere (halves random-gather traffic).
// R10: sentinel-padded branchless 8-load gather bursts. Regressed: VGPR cap
//      64 -> scratch spills. Structure right, register budget wrong.
// R11: launch_bounds(256,4) -> no spill, gather ~43.5 -> ~33 us. 212 us.
// R12: prep fusion (bin+cvt) + combine fused into gather. Only -4 us:
//      VGPR=84 proved the 64 resident weight regs made the compiler
//      serialize the gather burst (needs >=110 for 8 deep). Bubbles are
//      ~1 us (graph replay), prep+ellify ~75 us (later target).
// R13: weights evicted from regs during gather:
//      - W staged in 16 KB LDS (transposed bf16, XOR-swizzled); B-fragment
//        = one ds_read_b128, re-read per tile AFTER gather (LICM blocked
//        via opaque asm offset) so gather runs at low pressure.
//      - burst widened to 16 edges (16 uint4 in flight), 8-edge tail.
//      - launch_bounds(256,4), grid 1024 blocks, grid-stride over tiles.

#define D 64
#define CAP 64          // ELL row capacity
#define BNODES 256      // nodes per bucket (bucket = dst >> 8)
#define BCAP 4736       // bucket edge capacity: Poisson(4096), +10 sigma
#define MAXNB 512

typedef __bf16 bf16x8 __attribute__((ext_vector_type(8)));
typedef float  f32x4  __attribute__((ext_vector_type(4)));

__device__ __forceinline__ unsigned pack2(float a, float b) {
    __hip_bfloat162 t = __float22bfloat162_rn(make_float2(a, b));
    return *(unsigned*)&t;
}
__device__ __forceinline__ unsigned short f2b(float f) {
    __hip_bfloat16 b = __float2bfloat16(f);
    return *(unsigned short*)&b;
}

// ---- prep: bin (blocks [0, bin_blocks)) + cvt/zrow (rest) ---------------

__global__ void __launch_bounds__(256)
prep_kernel(const float4* __restrict__ x, uint4* __restrict__ xb4,
            unsigned* __restrict__ xsent, unsigned* __restrict__ h1sent,
            const int* __restrict__ src, const int* __restrict__ dst,
            int* __restrict__ gcur, int* __restrict__ gbucket,
            int E, int NB, int n8, int bin_blocks) {
    const int bid = blockIdx.x;
    const int t   = threadIdx.x;

    if (bid < bin_blocks) {
        // ---------------- bin part ----------------
        __shared__ int hist[MAXNB];
        for (int i = t; i < NB; i += 256) hist[i] = 0;
        __syncthreads();

        const int e4_total = E >> 2;
        const int base4    = bid * 1024;

        int4 sv[4], dv[4];
        bool have[4];
        #pragma unroll
        for (int k = 0; k < 4; ++k) {
            int i4 = base4 + t + k * 256;
            have[k] = i4 < e4_total;
            if (have[k]) {
                sv[k] = ((const int4*)src)[i4];
                dv[k] = ((const int4*)dst)[i4];
            }
        }

        #pragma unroll
        for (int k = 0; k < 4; ++k) if (have[k]) {
            atomicAdd(&hist[dv[k].x >> 8], 1);
            atomicAdd(&hist[dv[k].y >> 8], 1);
            atomicAdd(&hist[dv[k].z >> 8], 1);
            atomicAdd(&hist[dv[k].w >> 8], 1);
        }

        int  tail_s = 0, tail_d = 0;
        bool have_tail = false;
        if (bid == 0) {
            int e = (e4_total << 2) + t;
            if (e < E) {
                tail_s = src[e]; tail_d = dst[e]; have_tail = true;
                atomicAdd(&hist[tail_d >> 8], 1);
            }
        }
        __syncthreads();

        for (int i = t; i < NB; i += 256) {
            int c = hist[i];
            hist[i] = (c > 0) ? atomicAdd(&gcur[i], c) : 0;
        }
        __syncthreads();

        #pragma unroll
        for (int k = 0; k < 4; ++k) if (have[k]) {
            int4 s = sv[k], d = dv[k];
            int b, p;
            b = d.x >> 8; p = atomicAdd(&hist[b], 1); if (p < BCAP) gbucket[b * BCAP + p] = ((d.x & 255) << 17) | s.x;
            b = d.y >> 8; p = atomicAdd(&hist[b], 1); if (p < BCAP) gbucket[b * BCAP + p] = ((d.y & 255) << 17) | s.y;
            b = d.z >> 8; p = atomicAdd(&hist[b], 1); if (p < BCAP) gbucket[b * BCAP + p] = ((d.z & 255) << 17) | s.z;
            b = d.w >> 8; p = atomicAdd(&hist[b], 1); if (p < BCAP) gbucket[b * BCAP + p] = ((d.w & 255) << 17) | s.w;
        }
        if (have_tail) {
            int b = tail_d >> 8, p = atomicAdd(&hist[b], 1);
            if (p < BCAP) gbucket[b * BCAP + p] = ((tail_d & 255) << 17) | tail_s;
        }
        return;
    }

    // ---------------- cvt part ----------------
    const int cb = bid - bin_blocks;
    const int i  = cb * 256 + t;
    if (i < n8) {
        float4 a = x[2 * i], b = x[2 * i + 1];
        uint4 o;
        o.x = pack2(a.x, a.y);
        o.y = pack2(a.z, a.w);
        o.z = pack2(b.x, b.y);
        o.w = pack2(b.z, b.w);
        xb4[i] = o;
    }
    if (cb == 0 && t < 64) {                 // sentinel rows (index N) = 0
        if (t < 32) xsent[t] = 0u;
        else        h1sent[t - 32] = 0u;
    }
}

// ---- Phase 2: per-bucket ELL build (sentinel-padded to multiple of 8) ---

__global__ void __launch_bounds__(256)
ellify_kernel(const int* __restrict__ gcur, const int* __restrict__ gbucket,
              int* __restrict__ cnt, int* __restrict__ edge_idx, int N) {
    __shared__ int scnt[BNODES];
    scnt[threadIdx.x] = 0;
    __syncthreads();

    const int b     = blockIdx.x;
    const int ne    = min(gcur[b], BCAP);
    const int node0 = b << 8;

    for (int e = threadIdx.x; e < ne; e += 256) {
        int p   = gbucket[b * BCAP + e];
        int s   = p & 0x1FFFF;
        int ld  = p >> 17;
        int pos = atomicAdd(&scnt[ld], 1);
        if (pos < CAP) edge_idx[(size_t)(node0 + ld) * CAP + pos] = s;
    }
    __syncthreads();

    int node = node0 + threadIdx.x;
    if (node < N) {
        int raw = scnt[threadIdx.x];
        cnt[node] = raw;
        int c  = min(raw, CAP);
        int c8 = (c + 7) & ~7;
        for (int p = c; p < c8; ++p)
            edge_idx[(size_t)node * CAP + p] = N;   // sentinel: zero row
    }
}

// ---- fused gather + combine ---------------------------------------------

__device__ __forceinline__ void acc8(float& a0, float& a1, float& a2, float& a3,
                                     float& a4, float& a5, float& a6, float& a7,
                                     uint4 u) {
    a0 += __uint_as_float(u.x << 16);
    a1 += __uint_as_float(u.x & 0xffff0000u);
    a2 += __uint_as_float(u.y << 16);
    a3 += __uint_as_float(u.y & 0xffff0000u);
    a4 += __uint_as_float(u.z << 16);
    a5 += __uint_as_float(u.z & 0xffff0000u);
    a6 += __uint_as_float(u.w << 16);
    a7 += __uint_as_float(u.w & 0xffff0000u);
}

// gather one mean-row per 8-lane group; 16-edge branchless bursts + 8 tail
__device__ __forceinline__ uint4 gather_row(const uint4* __restrict__ h4,
                                            const int* __restrict__ cnt,
                                            const int* __restrict__ edge_idx,
                                            int node, int N, int q, int g) {
    const int count = (node < N) ? min(cnt[node], CAP) : 0;
    const int c8    = (count + 7) & ~7;
    const int start = node * CAP;
    const int b0    = g << 3;

    float a0 = 0.f, a1 = 0.f, a2 = 0.f, a3 = 0.f;
    float a4 = 0.f, a5 = 0.f, a6 = 0.f, a7 = 0.f;

    int j = 0;
    for (; j + 16 <= c8; j += 16) {
        const int srA = edge_idx[start + j + q];
        const int srB = edge_idx[start + j + 8 + q];
        const int s0  = __shfl(srA, b0 + 0, 64);
        const int s1  = __shfl(srA, b0 + 1, 64);
        const int s2  = __shfl(srA, b0 + 2, 64);
        const int s3  = __shfl(srA, b0 + 3, 64);
        const int s4  = __shfl(srA, b0 + 4, 64);
        const int s5  = __shfl(srA, b0 + 5, 64);
        const int s6  = __shfl(srA, b0 + 6, 64);
        const int s7  = __shfl(srA, b0 + 7, 64);
        const int s8  = __shfl(srB, b0 + 0, 64);
        const int s9  = __shfl(srB, b0 + 1, 64);
        const int s10 = __shfl(srB, b0 + 2, 64);
        const int s11 = __shfl(srB, b0 + 3, 64);
        const int s12 = __shfl(srB, b0 + 4, 64);
        const int s13 = __shfl(srB, b0 + 5, 64);
        const int s14 = __shfl(srB, b0 + 6, 64);
        const int s15 = __shfl(srB, b0 + 7, 64);
        uint4 u0  = h4[(size_t)s0  * 8 + q];
        uint4 u1  = h4[(size_t)s1  * 8 + q];
        uint4 u2  = h4[(size_t)s2  * 8 + q];
        uint4 u3  = h4[(size_t)s3  * 8 + q];
        uint4 u4  = h4[(size_t)s4  * 8 + q];
        uint4 u5  = h4[(size_t)s5  * 8 + q];
        uint4 u6  = h4[(size_t)s6  * 8 + q];
        uint4 u7  = h4[(size_t)s7  * 8 + q];
        uint4 u8  = h4[(size_t)s8  * 8 + q];
        uint4 u9  = h4[(size_t)s9  * 8 + q];
        uint4 u10 = h4[(size_t)s10 * 8 + q];
        uint4 u11 = h4[(size_t)s11 * 8 + q];
        uint4 u12 = h4[(size_t)s12 * 8 + q];
        uint4 u13 = h4[(size_t)s13 * 8 + q];
        uint4 u14 = h4[(size_t)s14 * 8 + q];
        uint4 u15 = h4[(size_t)s15 * 8 + q];
        acc8(a0, a1, a2, a3, a4, a5, a6, a7, u0);
        acc8(a0, a1, a2, a3, a4, a5, a6, a7, u1);
        acc8(a0, a1, a2, a3, a4, a5, a6, a7, u2);
        acc8(a0, a1, a2, a3, a4, a5, a6, a7, u3);
        acc8(a0, a1, a2, a3, a4, a5, a6, a7, u4);
        acc8(a0, a1, a2, a3, a4, a5, a6, a7, u5);
        acc8(a0, a1, a2, a3, a4, a5, a6, a7, u6);
        acc8(a0, a1, a2, a3, a4, a5, a6, a7, u7);
        acc8(a0, a1, a2, a3, a4, a5, a6, a7, u8);
        acc8(a0, a1, a2, a3, a4, a5, a6, a7, u9);
        acc8(a0, a1, a2, a3, a4, a5, a6, a7, u10);
        acc8(a0, a1, a2, a3, a4, a5, a6, a7, u11);
        acc8(a0, a1, a2, a3, a4, a5, a6, a7, u12);
        acc8(a0, a1, a2, a3, a4, a5, a6, a7, u13);
        acc8(a0, a1, a2, a3, a4, a5, a6, a7, u14);
        acc8(a0, a1, a2, a3, a4, a5, a6, a7, u15);
    }
    if (j < c8) {   // exactly 8 remain
        const int srA = edge_idx[start + j + q];
        const int s0 = __shfl(srA, b0 + 0, 64);
        const int s1 = __shfl(srA, b0 + 1, 64);
        const int s2 = __shfl(srA, b0 + 2, 64);
        const int s3 = __shfl(srA, b0 + 3, 64);
        const int s4 = __shfl(srA, b0 + 4, 64);
        const int s5 = __shfl(srA, b0 + 5, 64);
        const int s6 = __shfl(srA, b0 + 6, 64);
        const int s7 = __shfl(srA, b0 + 7, 64);
        uint4 u0 = h4[(size_t)s0 * 8 + q];
        uint4 u1 = h4[(size_t)s1 * 8 + q];
        uint4 u2 = h4[(size_t)s2 * 8 + q];
        uint4 u3 = h4[(size_t)s3 * 8 + q];
        uint4 u4 = h4[(size_t)s4 * 8 + q];
        uint4 u5 = h4[(size_t)s5 * 8 + q];
        uint4 u6 = h4[(size_t)s6 * 8 + q];
        uint4 u7 = h4[(size_t)s7 * 8 + q];
        acc8(a0, a1, a2, a3, a4, a5, a6, a7, u0);
        acc8(a0, a1, a2, a3, a4, a5, a6, a7, u1);
        acc8(a0, a1, a2, a3, a4, a5, a6, a7, u2);
        acc8(a0, a1, a2, a3, a4, a5, a6, a7, u3);
        acc8(a0, a1, a2, a3, a4, a5, a6, a7, u4);
        acc8(a0, a1, a2, a3, a4, a5, a6, a7, u5);
        acc8(a0, a1, a2, a3, a4, a5, a6, a7, u6);
        acc8(a0, a1, a2, a3, a4, a5, a6, a7, u7);
    }

    const float inv = 1.0f / fmaxf((float)count, 1.0f);
    uint4 o;
    o.x = pack2(a0 * inv, a1 * inv);
    o.y = pack2(a2 * inv, a3 * inv);
    o.z = pack2(a4 * inv, a5 * inv);
    o.w = pack2(a6 * inv, a7 * inv);
    return o;
}

__device__ __forceinline__ bf16x8 asbf(uint4 u) {
    union { uint4 a; bf16x8 v; } c; c.a = u; return c.v;
}

// LDS weight tile: transposed bf16, byte(col,k) = col*256 + ((k*2) ^ ((col&7)<<4))
// col = output column n (0..63); k = 0..63 self rows, 64..127 neigh rows.
__global__ void __launch_bounds__(256, 4)
fused_kernel(const unsigned short* __restrict__ h,
             const int* __restrict__ cnt,
             const int* __restrict__ edge_idx,
             const float* __restrict__ Wself,
             const float* __restrict__ Wneigh,
             const float* __restrict__ bias,
             float* __restrict__ out_f32,
             unsigned short* __restrict__ out_bf16, int N) {
    __shared__ unsigned short wt[8192];   // 16 KB

    {   // build LDS weight tile (once per block)
        const int t = threadIdx.x;
        for (int idx4 = t; idx4 < 2048; idx4 += 256) {
            const int k    = idx4 >> 4;          // 0..127
            const int col0 = (idx4 & 15) << 2;   // 0,4,...,60
            const float* W = (k < 64) ? (Wself + k * 64) : (Wneigh + (k - 64) * 64);
            float4 w = *(const float4*)(W + col0);
            #pragma unroll
            for (int e = 0; e < 4; ++e) {
                const int col = col0 + e;
                const float v = (e == 0) ? w.x : (e == 1) ? w.y : (e == 2) ? w.z : w.w;
                const int byte = col * 256 + (((k * 2)) ^ ((col & 7) << 4));
                wt[byte >> 1] = f2b(v);
            }
        }
    }
    __syncthreads();

    const int lane = threadIdx.x & 63;
    const int q    = lane & 7;
    const int g    = lane >> 3;
    const int col  = lane & 15;
    const int quad = lane >> 4;
    const int wave = blockIdx.x * (blockDim.x >> 6) + (threadIdx.x >> 6);
    const int n_waves = gridDim.x * (blockDim.x >> 6);

    float bv[4];
    #pragma unroll
    for (int nt = 0; nt < 4; ++nt) bv[nt] = bias[nt * 16 + col];

    const uint4* __restrict__ h4 = (const uint4*)h;   // row = 8 uint4

    const int tiles = (N + 15) >> 4;
    for (int t = wave; t < tiles; t += n_waves) {
        // ---- gather the tile's 16 mean-rows (2 rounds of 8) ----
        uint4 P0 = gather_row(h4, cnt, edge_idx, t * 16 + g,     N, q, g);

        int row = t * 16 + col;
        if (row >= N) row = N - 1;                    // stores are guarded
        uint4 A0u = h4[(size_t)row * 8 + quad];
        uint4 A1u = h4[(size_t)row * 8 + 4 + quad];

        uint4 P1 = gather_row(h4, cnt, edge_idx, t * 16 + 8 + g, N, q, g);

        // ---- redistribute P0/P1 -> A2/A3 fragments (16 shfl, no LDS) ----
        const int srcA2 = ((lane & 7) << 3) + quad;
        const int srcA3 = srcA2 + 4;
        const bool hi   = (lane & 8) != 0;            // m >= 8 -> round 1
        uint4 A2u, A3u;
        {
            unsigned l0 = __shfl(P0.x, srcA2, 64), h0 = __shfl(P1.x, srcA2, 64);
            unsigned l1 = __shfl(P0.y, srcA2, 64), h1 = __shfl(P1.y, srcA2, 64);
            unsigned l2 = __shfl(P0.z, srcA2, 64), h2 = __shfl(P1.z, srcA2, 64);
            unsigned l3 = __shfl(P0.w, srcA2, 64), h3 = __shfl(P1.w, srcA2, 64);
            A2u.x = hi ? h0 : l0;  A2u.y = hi ? h1 : l1;
            A2u.z = hi ? h2 : l2;  A2u.w = hi ? h3 : l3;
        }
        {
            unsigned l0 = __shfl(P0.x, srcA3, 64), h0 = __shfl(P1.x, srcA3, 64);
            unsigned l1 = __shfl(P0.y, srcA3, 64), h1 = __shfl(P1.y, srcA3, 64);
            unsigned l2 = __shfl(P0.z, srcA3, 64), h2 = __shfl(P1.z, srcA3, 64);
            unsigned l3 = __shfl(P0.w, srcA3, 64), h3 = __shfl(P1.w, srcA3, 64);
            A3u.x = hi ? h0 : l0;  A3u.y = hi ? h1 : l1;
            A3u.z = hi ? h2 : l2;  A3u.w = hi ? h3 : l3;
        }

        bf16x8 A0 = asbf(A0u), A1 = asbf(A1u);
        bf16x8 A2 = asbf(A2u), A3 = asbf(A3u);

        // ---- load B fragments from LDS (per tile, AFTER gather) ----
        // opaque base defeats LICM so Bf is not live during the gather
        int base = 0;
        asm volatile("" : "+v"(base));
        bf16x8 Bf[4][4];
        #pragma unroll
        for (int nt = 0; nt < 4; ++nt) {
            const int n = nt * 16 + col;
            #pragma unroll
            for (int kk = 0; kk < 4; ++kk) {
                const int kb2  = ((kk >= 2) ? 128 : 0) + (kk & 1) * 64 + quad * 16;
                const int byte = n * 256 + (kb2 ^ ((n & 7) << 4)) + base;
                Bf[nt][kk] = *(const bf16x8*)((const char*)wt + byte);
            }
        }

        // ---- combine: 16 MFMAs + stores ----
        #pragma unroll
        for (int nt = 0; nt < 4; ++nt) {
            f32x4 acc = {bv[nt], bv[nt], bv[nt], bv[nt]};
            acc = __builtin_amdgcn_mfma_f32_16x16x32_bf16(A0, Bf[nt][0], acc, 0, 0, 0);
            acc = __builtin_amdgcn_mfma_f32_16x16x32_bf16(A1, Bf[nt][1], acc, 0, 0, 0);
            acc = __builtin_amdgcn_mfma_f32_16x16x32_bf16(A2, Bf[nt][2], acc, 0, 0, 0);
            acc = __builtin_amdgcn_mfma_f32_16x16x32_bf16(A3, Bf[nt][3], acc, 0, 0, 0);
            if (out_f32) {
                #pragma unroll
                for (int r = 0; r < 4; ++r) {
                    const int orow = t * 16 + quad * 4 + r;
                    if (orow < N) out_f32[(size_t)orow * D + nt * 16 + col] = acc[r];
                }
            } else {
                #pragma unroll
                for (int r = 0; r < 4; ++r) {
                    const int orow = t * 16 + quad * 4 + r;
                    if (orow < N) out_bf16[(size_t)orow * D + nt * 16 + col] = f2b(acc[r]);
                }
            }
        }
    }
}

// -------------------------------------------------------------------------

extern "C" void kernel_launch(void* const* d_in, const int* in_sizes, int n_in,
                              void* d_out, int out_size, void* d_ws, size_t ws_size,
                              hipStream_t stream) {
    const float* x   = (const float*)d_in[0];
    const int*   src = (const int*)d_in[1];
    const int*   dst = (const int*)d_in[2];
    const float* Ws1 = (const float*)d_in[3];
    const float* Wn1 = (const float*)d_in[4];
    const float* b1  = (const float*)d_in[5];
    const float* Ws2 = (const float*)d_in[6];
    const float* Wn2 = (const float*)d_in[7];
    const float* b2  = (const float*)d_in[8];

    const int N = in_sizes[0] / D;   // 100000
    const int E = in_sizes[1];       // 1600000

    float* out = (float*)d_out;

    const int NB = (N + BNODES - 1) / BNODES;   // 391 buckets

    // Workspace: gcur[512] | cnt[N] | edge_idx[N*CAP] (25.6 MB) |
    //            xb[(N+1)*D] bf16 | h1b[(N+1)*D] bf16 | gbucket (7.4 MB)
    int* gcur      = (int*)d_ws;
    int* cnt       = gcur + 512;
    int* edge_idx  = cnt + N;
    unsigned short* xb   = (unsigned short*)(edge_idx + (size_t)N * CAP);
    unsigned short* h1b  = xb + (size_t)(N + 1) * D;
    int* gbucket   = (int*)(h1b + (size_t)(N + 1) * D);

    const int n8         = N * D / 8;
    const int cvt_blocks = (n8 + 255) / 256;
    const int e4_total   = E >> 2;
    const int bin_blocks = (e4_total + 1023) / 1024 > 0 ? (e4_total + 1023) / 1024 : 1;

    hipMemsetAsync(gcur, 0, 512 * sizeof(int), stream);

    // ---- prep: bin + cvt + sentinel zero, one dispatch ----
    prep_kernel<<<bin_blocks + cvt_blocks, 256, 0, stream>>>(
        (const float4*)x, (uint4*)xb,
        (unsigned*)(xb + (size_t)N * D), (unsigned*)(h1b + (size_t)N * D),
        src, dst, gcur, gbucket, E, NB, n8, bin_blocks);

    ellify_kernel<<<NB, 256, 0, stream>>>(gcur, gbucket, cnt, edge_idx, N);

    const int fblocks = 1024;   // 4 blocks/CU resident, grid-stride over tiles

    // ---- layer 1 (fused gather+combine, bf16 out) ----
    fused_kernel<<<fblocks, 256, 0, stream>>>(xb, cnt, edge_idx, Ws1, Wn1, b1,
                                              nullptr, h1b, N);
    // ---- layer 2 (fused, fp32 out) ----
    fused_kernel<<<fblocks, 256, 0, stream>>>(h1b, cnt, edge_idx, Ws2, Wn2, b2,
                                              out, nullptr, N);
}

// Round 5
// 202.563 us; speedup vs baseline: 1.0635x; 1.0635x over previous
//
#include <hip/hip_runtime.h>
#include <hip/hip_bf16.h>

// GraphSAGE 2-layer, mean agg, D=64, fp32 in/out.
// R9:  bf16 node features everywhere (halves random-gather traffic).
// R10: sentinel-padded branchless 8-load gather bursts. Regressed: VGPR cap
//      64 -> scratch spills. Structure right, register budget wrong.
// R11: launch_bounds(256,4) -> no spill, gather ~43.5 -> ~31 us. 212 us.
// R12: prep fusion (bin+cvt) + combine fused into gather (VGPR weights).
//      43.3 us fused, 207.8 total. VGPR=84: scheduler serialized the burst.
// R13: LDS-staged weights + 16-deep burst. Regressed (47.6): VGPR=64 +
//      spills (WRITE 12.5->42.7 MB) — the PRE-RA SCHEDULER sinks accumulates
//      between loads to minimize liveness; pressure-reduction can't fix it.
// R14: R12 structure + sched_barrier(0) fence between the 8 loads and the
//      8 accumulates of each burst (nothing crosses -> true depth-8 MLP,
//      allocator forced to hold 32 load regs) + next-burst edge_idx
//      prefetched before the fence. Weights back in VGPRs, no LDS.

#define D 64
#define CAP 64          // ELL row capacity
#define BNODES 256      // nodes per bucket (bucket = dst >> 8)
#define BCAP 4736       // bucket edge capacity: Poisson(4096), +10 sigma
#define MAXNB 512

typedef __bf16 bf16x8 __attribute__((ext_vector_type(8)));
typedef float  f32x4  __attribute__((ext_vector_type(4)));

__device__ __forceinline__ unsigned pack2(float a, float b) {
    __hip_bfloat162 t = __float22bfloat162_rn(make_float2(a, b));
    return *(unsigned*)&t;
}
__device__ __forceinline__ unsigned short f2b(float f) {
    __hip_bfloat16 b = __float2bfloat16(f);
    return *(unsigned short*)&b;
}

// ---- prep: bin (blocks [0, bin_blocks)) + cvt/zrow (rest) ---------------

__global__ void __launch_bounds__(256)
prep_kernel(const float4* __restrict__ x, uint4* __restrict__ xb4,
            unsigned* __restrict__ xsent, unsigned* __restrict__ h1sent,
            const int* __restrict__ src, const int* __restrict__ dst,
            int* __restrict__ gcur, int* __restrict__ gbucket,
            int E, int NB, int n8, int bin_blocks) {
    const int bid = blockIdx.x;
    const int t   = threadIdx.x;

    if (bid < bin_blocks) {
        // ---------------- bin part ----------------
        __shared__ int hist[MAXNB];
        for (int i = t; i < NB; i += 256) hist[i] = 0;
        __syncthreads();

        const int e4_total = E >> 2;
        const int base4    = bid * 1024;

        int4 sv[4], dv[4];
        bool have[4];
        #pragma unroll
        for (int k = 0; k < 4; ++k) {
            int i4 = base4 + t + k * 256;
            have[k] = i4 < e4_total;
            if (have[k]) {
                sv[k] = ((const int4*)src)[i4];
                dv[k] = ((const int4*)dst)[i4];
            }
        }

        #pragma unroll
        for (int k = 0; k < 4; ++k) if (have[k]) {
            atomicAdd(&hist[dv[k].x >> 8], 1);
            atomicAdd(&hist[dv[k].y >> 8], 1);
            atomicAdd(&hist[dv[k].z >> 8], 1);
            atomicAdd(&hist[dv[k].w >> 8], 1);
        }

        int  tail_s = 0, tail_d = 0;
        bool have_tail = false;
        if (bid == 0) {
            int e = (e4_total << 2) + t;
            if (e < E) {
                tail_s = src[e]; tail_d = dst[e]; have_tail = true;
                atomicAdd(&hist[tail_d >> 8], 1);
            }
        }
        __syncthreads();

        for (int i = t; i < NB; i += 256) {
            int c = hist[i];
            hist[i] = (c > 0) ? atomicAdd(&gcur[i], c) : 0;
        }
        __syncthreads();

        #pragma unroll
        for (int k = 0; k < 4; ++k) if (have[k]) {
            int4 s = sv[k], d = dv[k];
            int b, p;
            b = d.x >> 8; p = atomicAdd(&hist[b], 1); if (p < BCAP) gbucket[b * BCAP + p] = ((d.x & 255) << 17) | s.x;
            b = d.y >> 8; p = atomicAdd(&hist[b], 1); if (p < BCAP) gbucket[b * BCAP + p] = ((d.y & 255) << 17) | s.y;
            b = d.z >> 8; p = atomicAdd(&hist[b], 1); if (p < BCAP) gbucket[b * BCAP + p] = ((d.z & 255) << 17) | s.z;
            b = d.w >> 8; p = atomicAdd(&hist[b], 1); if (p < BCAP) gbucket[b * BCAP + p] = ((d.w & 255) << 17) | s.w;
        }
        if (have_tail) {
            int b = tail_d >> 8, p = atomicAdd(&hist[b], 1);
            if (p < BCAP) gbucket[b * BCAP + p] = ((tail_d & 255) << 17) | tail_s;
        }
        return;
    }

    // ---------------- cvt part ----------------
    const int cb = bid - bin_blocks;
    const int i  = cb * 256 + t;
    if (i < n8) {
        float4 a = x[2 * i], b = x[2 * i + 1];
        uint4 o;
        o.x = pack2(a.x, a.y);
        o.y = pack2(a.z, a.w);
        o.z = pack2(b.x, b.y);
        o.w = pack2(b.z, b.w);
        xb4[i] = o;
    }
    if (cb == 0 && t < 64) {                 // sentinel rows (index N) = 0
        if (t < 32) xsent[t] = 0u;
        else        h1sent[t - 32] = 0u;
    }
}

// ---- Phase 2: per-bucket ELL build (sentinel-padded to multiple of 8) ---

__global__ void __launch_bounds__(256)
ellify_kernel(const int* __restrict__ gcur, const int* __restrict__ gbucket,
              int* __restrict__ cnt, int* __restrict__ edge_idx, int N) {
    __shared__ int scnt[BNODES];
    scnt[threadIdx.x] = 0;
    __syncthreads();

    const int b     = blockIdx.x;
    const int ne    = min(gcur[b], BCAP);
    const int node0 = b << 8;

    for (int e = threadIdx.x; e < ne; e += 256) {
        int p   = gbucket[b * BCAP + e];
        int s   = p & 0x1FFFF;
        int ld  = p >> 17;
        int pos = atomicAdd(&scnt[ld], 1);
        if (pos < CAP) edge_idx[(size_t)(node0 + ld) * CAP + pos] = s;
    }
    __syncthreads();

    int node = node0 + threadIdx.x;
    if (node < N) {
        int raw = scnt[threadIdx.x];
        cnt[node] = raw;
        int c  = min(raw, CAP);
        int c8 = (c + 7) & ~7;
        for (int p = c; p < c8; ++p)
            edge_idx[(size_t)node * CAP + p] = N;   // sentinel: zero row
    }
}

// ---- fused gather + combine ---------------------------------------------

__device__ __forceinline__ void acc8(float& a0, float& a1, float& a2, float& a3,
                                     float& a4, float& a5, float& a6, float& a7,
                                     uint4 u) {
    a0 += __uint_as_float(u.x << 16);
    a1 += __uint_as_float(u.x & 0xffff0000u);
    a2 += __uint_as_float(u.y << 16);
    a3 += __uint_as_float(u.y & 0xffff0000u);
    a4 += __uint_as_float(u.z << 16);
    a5 += __uint_as_float(u.z & 0xffff0000u);
    a6 += __uint_as_float(u.w << 16);
    a7 += __uint_as_float(u.w & 0xffff0000u);
}

// gather one mean-row per 8-lane group; branchless 8-load bursts.
// sched_barrier(0) between loads and accumulates pins true depth-8 MLP
// (the pre-RA scheduler otherwise sinks adds between loads to cut
// liveness — the R10/R12/R13 failure mode). Next burst's edge_idx word
// is prefetched before the fence so its latency hides under the adds.
__device__ __forceinline__ uint4 gather_row8(const uint4* __restrict__ h4,
                                             const int* __restrict__ cnt,
                                             const int* __restrict__ edge_idx,
                                             int node, int N, int q, int g) {
    const int nodec = (node < N) ? node : (N - 1);
    const int count = (node < N) ? min(cnt[nodec], CAP) : 0;
    const int c8    = (count + 7) & ~7;
    const int start = nodec * CAP;
    const int b0    = g << 3;

    float a0 = 0.f, a1 = 0.f, a2 = 0.f, a3 = 0.f;
    float a4 = 0.f, a5 = 0.f, a6 = 0.f, a7 = 0.f;

    int sreg = edge_idx[start + q];   // in-bounds; unused if c8 == 0

    for (int j = 0; j < c8; j += 8) {
        const int jn = j + 8;
        const int jc = (jn < c8) ? jn : 0;               // address clamp, no mask
        const int sreg_next = edge_idx[start + jc + q];  // prefetch next burst

        const int s0 = __shfl(sreg, b0 + 0, 64);
        const int s1 = __shfl(sreg, b0 + 1, 64);
        const int s2 = __shfl(sreg, b0 + 2, 64);
        const int s3 = __shfl(sreg, b0 + 3, 64);
        const int s4 = __shfl(sreg, b0 + 4, 64);
        const int s5 = __shfl(sreg, b0 + 5, 64);
        const int s6 = __shfl(sreg, b0 + 6, 64);
        const int s7 = __shfl(sreg, b0 + 7, 64);
        uint4 u0 = h4[(size_t)s0 * 8 + q];
        uint4 u1 = h4[(size_t)s1 * 8 + q];
        uint4 u2 = h4[(size_t)s2 * 8 + q];
        uint4 u3 = h4[(size_t)s3 * 8 + q];
        uint4 u4 = h4[(size_t)s4 * 8 + q];
        uint4 u5 = h4[(size_t)s5 * 8 + q];
        uint4 u6 = h4[(size_t)s6 * 8 + q];
        uint4 u7 = h4[(size_t)s7 * 8 + q];

        __builtin_amdgcn_sched_barrier(0);   // all 8 loads issued before any add

        acc8(a0, a1, a2, a3, a4, a5, a6, a7, u0);
        acc8(a0, a1, a2, a3, a4, a5, a6, a7, u1);
        acc8(a0, a1, a2, a3, a4, a5, a6, a7, u2);
        acc8(a0, a1, a2, a3, a4, a5, a6, a7, u3);
        acc8(a0, a1, a2, a3, a4, a5, a6, a7, u4);
        acc8(a0, a1, a2, a3, a4, a5, a6, a7, u5);
        acc8(a0, a1, a2, a3, a4, a5, a6, a7, u6);
        acc8(a0, a1, a2, a3, a4, a5, a6, a7, u7);

        sreg = sreg_next;
    }

    const float inv = 1.0f / fmaxf((float)count, 1.0f);
    uint4 o;
    o.x = pack2(a0 * inv, a1 * inv);
    o.y = pack2(a2 * inv, a3 * inv);
    o.z = pack2(a4 * inv, a5 * inv);
    o.w = pack2(a6 * inv, a7 * inv);
    return o;
}

__device__ __forceinline__ bf16x8 cvt8(float4 a, float4 b) {
    union { bf16x8 v; __hip_bfloat162 p[4]; } u;
    u.p[0] = __float22bfloat162_rn(make_float2(a.x, a.y));
    u.p[1] = __float22bfloat162_rn(make_float2(a.z, a.w));
    u.p[2] = __float22bfloat162_rn(make_float2(b.x, b.y));
    u.p[3] = __float22bfloat162_rn(make_float2(b.z, b.w));
    return u.v;
}
__device__ __forceinline__ bf16x8 asbf(uint4 u) {
    union { uint4 a; bf16x8 v; } c; c.a = u; return c.v;
}

__global__ void __launch_bounds__(256, 3)
fused_kernel(const unsigned short* __restrict__ h,
             const int* __restrict__ cnt,
             const int* __restrict__ edge_idx,
             const float* __restrict__ Wself,
             const float* __restrict__ Wneigh,
             const float* __restrict__ bias,
             float* __restrict__ out_f32,
             unsigned short* __restrict__ out_bf16, int N) {
    const int lane = threadIdx.x & 63;
    const int q    = lane & 7;
    const int g    = lane >> 3;
    const int col  = lane & 15;
    const int quad = lane >> 4;
    const int wave = blockIdx.x * (blockDim.x >> 6) + (threadIdx.x >> 6);
    const int n_waves = gridDim.x * (blockDim.x >> 6);

    // B fragments in VGPRs (per wave, reused across all tiles)
    bf16x8 Bf[4][4];
    #pragma unroll
    for (int nt = 0; nt < 4; ++nt) {
        const int n = nt * 16 + col;
        #pragma unroll
        for (int kk = 0; kk < 4; ++kk) {
            const float* W = (kk < 2) ? Wself : Wneigh;
            const int kbase = (kk & 1) * 32 + quad * 8;
            float w0 = W[(kbase + 0) * D + n];
            float w1 = W[(kbase + 1) * D + n];
            float w2 = W[(kbase + 2) * D + n];
            float w3 = W[(kbase + 3) * D + n];
            float w4 = W[(kbase + 4) * D + n];
            float w5 = W[(kbase + 5) * D + n];
            float w6 = W[(kbase + 6) * D + n];
            float w7 = W[(kbase + 7) * D + n];
            Bf[nt][kk] = cvt8(make_float4(w0, w1, w2, w3), make_float4(w4, w5, w6, w7));
        }
    }

    float bv[4];
    #pragma unroll
    for (int nt = 0; nt < 4; ++nt) bv[nt] = bias[nt * 16 + col];

    const uint4* __restrict__ h4 = (const uint4*)h;   // row = 8 uint4

    const int tiles = (N + 15) >> 4;
    for (int t = wave; t < tiles; t += n_waves) {
        // ---- gather the tile's 16 mean-rows (2 rounds of 8) ----
        uint4 P0 = gather_row8(h4, cnt, edge_idx, t * 16 + g,     N, q, g);

        int row = t * 16 + col;
        if (row >= N) row = N - 1;                    // stores are guarded
        uint4 A0u = h4[(size_t)row * 8 + quad];
        uint4 A1u = h4[(size_t)row * 8 + 4 + quad];

        uint4 P1 = gather_row8(h4, cnt, edge_idx, t * 16 + 8 + g, N, q, g);

        // ---- redistribute P0/P1 -> A2/A3 fragments (16 shfl, no LDS) ----
        const int srcA2 = ((lane & 7) << 3) + quad;
        const int srcA3 = srcA2 + 4;
        const bool hi   = (lane & 8) != 0;            // m >= 8 -> round 1
        uint4 A2u, A3u;
        {
            unsigned l0 = __shfl(P0.x, srcA2, 64), h0 = __shfl(P1.x, srcA2, 64);
            unsigned l1 = __shfl(P0.y, srcA2, 64), h1 = __shfl(P1.y, srcA2, 64);
            unsigned l2 = __shfl(P0.z, srcA2, 64), h2 = __shfl(P1.z, srcA2, 64);
            unsigned l3 = __shfl(P0.w, srcA2, 64), h3 = __shfl(P1.w, srcA2, 64);
            A2u.x = hi ? h0 : l0;  A2u.y = hi ? h1 : l1;
            A2u.z = hi ? h2 : l2;  A2u.w = hi ? h3 : l3;
        }
        {
            unsigned l0 = __shfl(P0.x, srcA3, 64), h0 = __shfl(P1.x, srcA3, 64);
            unsigned l1 = __shfl(P0.y, srcA3, 64), h1 = __shfl(P1.y, srcA3, 64);
            unsigned l2 = __shfl(P0.z, srcA3, 64), h2 = __shfl(P1.z, srcA3, 64);
            unsigned l3 = __shfl(P0.w, srcA3, 64), h3 = __shfl(P1.w, srcA3, 64);
            A3u.x = hi ? h0 : l0;  A3u.y = hi ? h1 : l1;
            A3u.z = hi ? h2 : l2;  A3u.w = hi ? h3 : l3;
        }

        bf16x8 A0 = asbf(A0u), A1 = asbf(A1u);
        bf16x8 A2 = asbf(A2u), A3 = asbf(A3u);

        // ---- combine: 16 MFMAs + stores ----
        #pragma unroll
        for (int nt = 0; nt < 4; ++nt) {
            f32x4 acc = {bv[nt], bv[nt], bv[nt], bv[nt]};
            acc = __builtin_amdgcn_mfma_f32_16x16x32_bf16(A0, Bf[nt][0], acc, 0, 0, 0);
            acc = __builtin_amdgcn_mfma_f32_16x16x32_bf16(A1, Bf[nt][1], acc, 0, 0, 0);
            acc = __builtin_amdgcn_mfma_f32_16x16x32_bf16(A2, Bf[nt][2], acc, 0, 0, 0);
            acc = __builtin_amdgcn_mfma_f32_16x16x32_bf16(A3, Bf[nt][3], acc, 0, 0, 0);
            if (out_f32) {
                #pragma unroll
                for (int r = 0; r < 4; ++r) {
                    const int orow = t * 16 + quad * 4 + r;
                    if (orow < N) out_f32[(size_t)orow * D + nt * 16 + col] = acc[r];
                }
            } else {
                #pragma unroll
                for (int r = 0; r < 4; ++r) {
                    const int orow = t * 16 + quad * 4 + r;
                    if (orow < N) out_bf16[(size_t)orow * D + nt * 16 + col] = f2b(acc[r]);
                }
            }
        }
    }
}

// -------------------------------------------------------------------------

extern "C" void kernel_launch(void* const* d_in, const int* in_sizes, int n_in,
                              void* d_out, int out_size, void* d_ws, size_t ws_size,
                              hipStream_t stream) {
    const float* x   = (const float*)d_in[0];
    const int*   src = (const int*)d_in[1];
    const int*   dst = (const int*)d_in[2];
    const float* Ws1 = (const float*)d_in[3];
    const float* Wn1 = (const float*)d_in[4];
    const float* b1  = (const float*)d_in[5];
    const float* Ws2 = (const float*)d_in[6];
    const float* Wn2 = (const float*)d_in[7];
    const float* b2  = (const float*)d_in[8];

    const int N = in_sizes[0] / D;   // 100000
    const int E = in_sizes[1];       // 1600000

    float* out = (float*)d_out;

    const int NB = (N + BNODES - 1) / BNODES;   // 391 buckets

    // Workspace: gcur[512] | cnt[N] | edge_idx[N*CAP] (25.6 MB) |
    //            xb[(N+1)*D] bf16 | h1b[(N+1)*D] bf16 | gbucket (7.4 MB)
    int* gcur      = (int*)d_ws;
    int* cnt       = gcur + 512;
    int* edge_idx  = cnt + N;
    unsigned short* xb   = (unsigned short*)(edge_idx + (size_t)N * CAP);
    unsigned short* h1b  = xb + (size_t)(N + 1) * D;
    int* gbucket   = (int*)(h1b + (size_t)(N + 1) * D);

    const int n8         = N * D / 8;
    const int cvt_blocks = (n8 + 255) / 256;
    const int e4_total   = E >> 2;
    const int bin_blocks = (e4_total + 1023) / 1024 > 0 ? (e4_total + 1023) / 1024 : 1;

    hipMemsetAsync(gcur, 0, 512 * sizeof(int), stream);

    // ---- prep: bin + cvt + sentinel zero, one dispatch ----
    prep_kernel<<<bin_blocks + cvt_blocks, 256, 0, stream>>>(
        (const float4*)x, (uint4*)xb,
        (unsigned*)(xb + (size_t)N * D), (unsigned*)(h1b + (size_t)N * D),
        src, dst, gcur, gbucket, E, NB, n8, bin_blocks);

    ellify_kernel<<<NB, 256, 0, stream>>>(gcur, gbucket, cnt, edge_idx, N);

    const int tiles   = (N + 15) / 16;
    const int fblocks = (tiles + 3) / 4;        // 1 tile per wave

    // ---- layer 1 (fused gather+combine, bf16 out) ----
    fused_kernel<<<fblocks, 256, 0, stream>>>(xb, cnt, edge_idx, Ws1, Wn1, b1,
                                              nullptr, h1b, N);
    // ---- layer 2 (fused, fp32 out) ----
    fused_kernel<<<fblocks, 256, 0, stream>>>(h1b, cnt, edge_idx, Ws2, Wn2, b2,
                                              out, nullptr, N);
}